// Round 1
// baseline (11860.552 us; speedup 1.0000x reference)
//
#include <hip/hip_runtime.h>
#include <hip/hip_bf16.h>

#define N 4096
#define D 512
#define NBLK 1024
#define LA (-8.317766166719343f)            // -log(4096)
#define LAB1 (-16.635532333438686f - 1.0f)  // la + lb + 1

typedef unsigned short u16;
typedef __attribute__((ext_vector_type(8))) short short8;
typedef __attribute__((ext_vector_type(8))) unsigned short ushort8;
typedef __attribute__((ext_vector_type(4))) float fvec4;

static __device__ __forceinline__ float bf2f(unsigned short u) {
    union { unsigned int i; float f; } c;
    c.i = ((unsigned int)u) << 16;
    return c.f;
}

static __device__ __forceinline__ unsigned short f2bf(float x) {
    __hip_bfloat16 h = __float2bfloat16(x);  // RNE
    unsigned short u;
    __builtin_memcpy(&u, &h, 2);
    return u;
}

static __device__ __forceinline__ void gld_lds16(const u16* gp, u16* lp) {
    __builtin_amdgcn_global_load_lds(
        (__attribute__((address_space(1))) void*)(u16*)gp,
        (__attribute__((address_space(3))) void*)lp, 16, 0, 0);
}

// ---------------- fp32 -> bf16 convert (8 elems/thread) ----------------
__global__ __launch_bounds__(256) void f32_to_bf16_k(const float* __restrict__ in,
                                                     u16* __restrict__ out) {
    int idx = blockIdx.x * 256 + threadIdx.x;
    fvec4 a = *((const fvec4*)in + idx * 2);
    fvec4 b = *((const fvec4*)in + idx * 2 + 1);
    ushort8 o;
#pragma unroll
    for (int e = 0; e < 4; ++e) { o[e] = f2bf(a[e]); o[4 + e] = f2bf(b[e]); }
    *((ushort8*)out + idx) = o;
}

// ---------------- row squared-norms: one wave per row ----------------
__global__ __launch_bounds__(256) void row_norms_k(const float* __restrict__ X,
                                                   float* __restrict__ out) {
    int wave = threadIdx.x >> 6;
    int lane = threadIdx.x & 63;
    int row  = blockIdx.x * 4 + wave;
    const float* xr = X + (size_t)row * D;
    float s = 0.f;
#pragma unroll
    for (int k = 0; k < D / 64; ++k) {
        float v = xr[lane + 64 * k];
        s += v * v;
    }
#pragma unroll
    for (int off = 32; off >= 1; off >>= 1) s += __shfl_down(s, off);
    if (lane == 0) out[row] = s;
}

// ---------------- cost matrix via bf16 MFMA (m97 pattern) ----------------
__global__ __launch_bounds__(256) void gemm_cost_bf16_k(const u16* __restrict__ A,
                                                        const u16* __restrict__ B,
                                                        const float* __restrict__ x2,
                                                        const float* __restrict__ y2,
                                                        u16* __restrict__ M) {
    __shared__ u16 As[128 * 32];
    __shared__ u16 Bs[128 * 32];
    int tid = threadIdx.x;
    int wave = tid >> 6, lane = tid & 63;
    int i0 = blockIdx.y * 128, j0 = blockIdx.x * 128;
    int wr = (wave >> 1) * 64, wc = (wave & 1) * 64;

    fvec4 acc[4][4] = {};

    int srow = wave * 16 + (lane >> 2);
    int skk  = (lane & 3) * 8;
    const u16* ga0 = A + (size_t)(i0 + srow) * D + skk;
    const u16* ga1 = A + (size_t)(i0 + 64 + srow) * D + skk;
    const u16* gb0 = B + (size_t)(j0 + srow) * D + skk;
    const u16* gb1 = B + (size_t)(j0 + 64 + srow) * D + skk;
    u16* la0 = &As[(wave * 16) * 32];
    u16* la1 = &As[(64 + wave * 16) * 32];
    u16* lb0 = &Bs[(wave * 16) * 32];
    u16* lb1 = &Bs[(64 + wave * 16) * 32];

    int fr = lane & 15, q = lane >> 4;

    for (int k0 = 0; k0 < D; k0 += 32) {
        __syncthreads();
        gld_lds16(ga0 + k0, la0);
        gld_lds16(ga1 + k0, la1);
        gld_lds16(gb0 + k0, lb0);
        gld_lds16(gb1 + k0, lb1);
        __syncthreads();
        short8 af[4], bf[4];
#pragma unroll
        for (int t = 0; t < 4; ++t) {
            af[t] = *(const short8*)&As[(wr + t * 16 + fr) * 32 + q * 8];
            bf[t] = *(const short8*)&Bs[(wc + t * 16 + fr) * 32 + q * 8];
        }
#pragma unroll
        for (int ri = 0; ri < 4; ++ri)
#pragma unroll
            for (int ci = 0; ci < 4; ++ci)
                acc[ri][ci] = __builtin_amdgcn_mfma_f32_16x16x32_bf16(af[ri], bf[ci],
                                                                      acc[ri][ci], 0, 0, 0);
    }

#pragma unroll
    for (int ri = 0; ri < 4; ++ri) {
#pragma unroll
        for (int ci = 0; ci < 4; ++ci) {
            int j = j0 + wc + ci * 16 + fr;
            float yj = y2[j];
#pragma unroll
            for (int r = 0; r < 4; ++r) {
                int i = i0 + wr + ri * 16 + q * 4 + r;
                float val = fmaxf(x2[i] + yj - 2.0f * acc[ri][ci][r], 0.0f);
                M[(size_t)i * N + j] = f2bf(val);
            }
        }
    }
}

// ---------------- bf16 LDS-tiled transpose ----------------
__global__ __launch_bounds__(256) void transpose_bf16_k(const u16* __restrict__ in,
                                                        u16* __restrict__ out) {
    __shared__ u16 tile[64][66];
    int bx = blockIdx.x * 64, by = blockIdx.y * 64;
    int tx = threadIdx.x & 63, ty = threadIdx.x >> 6;
#pragma unroll
    for (int r = 0; r < 64; r += 4)
        tile[r + ty][tx] = in[(size_t)(by + r + ty) * N + bx + tx];
    __syncthreads();
#pragma unroll
    for (int r = 0; r < 64; r += 4)
        out[(size_t)(bx + r + ty) * N + by + tx] = tile[tx][r + ty];
}

// =====================================================================
// Persistent cooperative Sinkhorn: 100 iterations + final value, 1 launch.
// Grid: 1024 blocks x 256 threads (4 blocks/CU, co-resident).
// One row per wave per half-step (1024 blocks * 4 waves = 4096 rows).
// =====================================================================

// Hierarchical grid barrier.
//  - cnt: 64 counters, each on its own 128B line; block b arrives on cnt[b&63].
//    Counters are monotonic (never reset) -> no reset race; target = round*NBLK.
//  - gen: 64 mirrored generation words (one per group line) published by the
//    master wave (block 0, wave 0) after it observes all arrivals.
//  - __threadfence() (agent scope) on the release and acquire sides handles
//    cross-XCD L2 non-coherence (wbl2 / inv are cache-wide ops).
static __device__ __forceinline__ void gsync(unsigned* cnt, unsigned* gen, unsigned round) {
    __syncthreads();
    if (blockIdx.x == 0) {
        if (threadIdx.x < 64) {
            int lane = threadIdx.x;
            __threadfence();  // release block 0's prior writes
            if (lane == 0)
                __hip_atomic_fetch_add(&cnt[0], 1u, __ATOMIC_RELAXED, __HIP_MEMORY_SCOPE_AGENT);
            unsigned target = round * NBLK;
            for (;;) {
                unsigned c = __hip_atomic_load(&cnt[lane << 5], __ATOMIC_RELAXED,
                                               __HIP_MEMORY_SCOPE_AGENT);
#pragma unroll
                for (int off = 32; off >= 1; off >>= 1)
                    c += (unsigned)__shfl_xor((int)c, off);
                if (c >= target) break;
                __builtin_amdgcn_s_sleep(2);
            }
            __threadfence();  // acquire (inv) before publish; also orders publish after wb
            __hip_atomic_store(&gen[lane << 5], round, __ATOMIC_RELAXED,
                               __HIP_MEMORY_SCOPE_AGENT);
        }
    } else if (threadIdx.x == 0) {
        __threadfence();  // release this block's prior writes (wbl2)
        __hip_atomic_fetch_add(&cnt[(blockIdx.x & 63) << 5], 1u, __ATOMIC_RELAXED,
                               __HIP_MEMORY_SCOPE_AGENT);
        unsigned idx = (blockIdx.x & 63) << 5;
        while (__hip_atomic_load(&gen[idx], __ATOMIC_RELAXED, __HIP_MEMORY_SCOPE_AGENT) < round)
            __builtin_amdgcn_s_sleep(4);
        __threadfence();  // acquire (invalidate L1/L2) before reading new f/g
    }
    __syncthreads();
}

// One Sinkhorn half-step: vout[row] = logw - LSE_j( vin[j] - R[row][j] ).
// One row per wave; exact LSE in two 32-element register groups (caps VGPRs).
static __device__ __forceinline__ void half_step(const u16* __restrict__ R,
                                                 const float* __restrict__ vin,
                                                 float* __restrict__ vout,
                                                 float logw) {
    int wid = (blockIdx.x << 2) | (threadIdx.x >> 6);  // row 0..4095
    int lane = threadIdx.x & 63;
    const u16* row = R + ((size_t)wid << 12);
    float m = 0.f, s = 0.f;
#pragma unroll 1
    for (int h = 0; h < 2; ++h) {
        float tv[32];
#pragma unroll
        for (int c = 0; c < 4; ++c) {
            int j = (h * 4 + c) * 512 + lane * 8;
            ushort8 m8 = *(const ushort8*)(row + j);
            fvec4 g0 = *(const fvec4*)(vin + j);
            fvec4 g1 = *(const fvec4*)(vin + j + 4);
            const unsigned* mu = (const unsigned*)&m8;
#pragma unroll
            for (int k = 0; k < 4; ++k) {
                unsigned u = mu[k];
                float flo = __uint_as_float(u << 16);          // elem 2k
                float fhi = __uint_as_float(u & 0xffff0000u);  // elem 2k+1
                float ga = (k < 2) ? g0[2 * k] : g1[2 * k - 4];
                float gb = (k < 2) ? g0[2 * k + 1] : g1[2 * k - 3];
                tv[c * 8 + 2 * k]     = ga - flo;
                tv[c * 8 + 2 * k + 1] = gb - fhi;
            }
        }
        float mh = tv[0];
#pragma unroll
        for (int e = 1; e < 32; ++e) mh = fmaxf(mh, tv[e]);
        float sh = 0.f;
#pragma unroll
        for (int e = 0; e < 32; ++e) sh += __expf(tv[e] - mh);
        if (h == 0) { m = mh; s = sh; }
        else {
            float mn = fmaxf(m, mh);
            s = s * __expf(m - mn) + sh * __expf(mh - mn);
            m = mn;
        }
    }
#pragma unroll
    for (int off = 32; off >= 1; off >>= 1) {
        float mo = __shfl_xor(m, off);
        float so = __shfl_xor(s, off);
        float mn = fmaxf(m, mo);
        s = s * __expf(m - mn) + so * __expf(mo - mn);
        m = mn;
    }
    if (lane == 0) vout[wid] = logw - (m + __logf(s));
}

// Per-wave objective partial: sum_j exp(f_i + g_j - M_ij) * (f_i + g_j - la - lb - 1)
static __device__ __forceinline__ float value_rows(const u16* __restrict__ M,
                                                   const float* __restrict__ f,
                                                   const float* __restrict__ g) {
    int wid = (blockIdx.x << 2) | (threadIdx.x >> 6);
    int lane = threadIdx.x & 63;
    const u16* row = M + ((size_t)wid << 12);
    float fi = f[wid];
    float local = 0.f;
#pragma unroll 1
    for (int c = 0; c < 8; ++c) {
        int j = c * 512 + lane * 8;
        ushort8 m8 = *(const ushort8*)(row + j);
        fvec4 g0 = *(const fvec4*)(g + j);
        fvec4 g1 = *(const fvec4*)(g + j + 4);
        const unsigned* mu = (const unsigned*)&m8;
#pragma unroll
        for (int k = 0; k < 4; ++k) {
            unsigned u = mu[k];
            float mv0 = __uint_as_float(u << 16);
            float mv1 = __uint_as_float(u & 0xffff0000u);
            float ga = (k < 2) ? g0[2 * k] : g1[2 * k - 4];
            float gb = (k < 2) ? g0[2 * k + 1] : g1[2 * k - 3];
            float a0 = fi + ga, a1 = fi + gb;
            local += __expf(a0 - mv0) * (a0 - LAB1);
            local += __expf(a1 - mv1) * (a1 - LAB1);
        }
    }
#pragma unroll
    for (int off = 32; off >= 1; off >>= 1) local += __shfl_xor(local, off);
    return local;
}

__global__ __launch_bounds__(256, 4) void sinkhorn_persist_k(
        const u16* __restrict__ Mb, const u16* __restrict__ MTb,
        float* __restrict__ f, float* __restrict__ g,
        unsigned* cnt, unsigned* gen,
        float* __restrict__ partial, float* __restrict__ out) {
    __shared__ float ps[4];
    __shared__ float fs[4];
    unsigned round = 0;
    for (int it = 0; it < 100; ++it) {
        half_step(Mb, g, f, LA);
        gsync(cnt, gen, ++round);
        half_step(MTb, f, g, LA);
        gsync(cnt, gen, ++round);
    }
    // final objective (M row pass), no global atomics
    float local = value_rows(Mb, f, g);
    if ((threadIdx.x & 63) == 0) ps[threadIdx.x >> 6] = local;
    __syncthreads();
    if (threadIdx.x == 0) partial[blockIdx.x] = ps[0] + ps[1] + ps[2] + ps[3];
    gsync(cnt, gen, ++round);
    if (blockIdx.x == 0) {
        int t = threadIdx.x;
        float s2 = partial[t] + partial[t + 256] + partial[t + 512] + partial[t + 768];
#pragma unroll
        for (int off = 32; off >= 1; off >>= 1) s2 += __shfl_xor(s2, off);
        if ((t & 63) == 0) fs[t >> 6] = s2;
        __syncthreads();
        if (t == 0) out[0] = fs[0] + fs[1] + fs[2] + fs[3] + 1.0f;
    }
}

// ---------------- fallback path (previous verified kernels) ----------------
__global__ __launch_bounds__(256) void sinkhorn_half_bf16_k(const u16* __restrict__ Mr,
                                                            const float* __restrict__ vin,
                                                            float* __restrict__ vout,
                                                            float logw) {
    int row = blockIdx.x;
    const u16* Mrow = Mr + (size_t)row * N;
    int t = threadIdx.x;
    ushort8 m0 = *(const ushort8*)(Mrow + t * 8);
    ushort8 m1 = *(const ushort8*)(Mrow + 2048 + t * 8);
    fvec4 ga0 = *(const fvec4*)(vin + t * 8);
    fvec4 ga1 = *(const fvec4*)(vin + t * 8 + 4);
    fvec4 gb0 = *(const fvec4*)(vin + 2048 + t * 8);
    fvec4 gb1 = *(const fvec4*)(vin + 2048 + t * 8 + 4);
    float tv[16];
#pragma unroll
    for (int e = 0; e < 4; ++e) {
        tv[e]      = ga0[e] - bf2f(m0[e]);
        tv[4 + e]  = ga1[e] - bf2f(m0[4 + e]);
        tv[8 + e]  = gb0[e] - bf2f(m1[e]);
        tv[12 + e] = gb1[e] - bf2f(m1[4 + e]);
    }
    float m = tv[0];
#pragma unroll
    for (int e = 1; e < 16; ++e) m = fmaxf(m, tv[e]);
    float s = 0.f;
#pragma unroll
    for (int e = 0; e < 16; ++e) s += __expf(tv[e] - m);
#pragma unroll
    for (int off = 32; off >= 1; off >>= 1) {
        float mo = __shfl_down(m, off);
        float so = __shfl_down(s, off);
        float mn = fmaxf(m, mo);
        s = s * __expf(m - mn) + so * __expf(mo - mn);
        m = mn;
    }
    __shared__ float sm[4], ss[4];
    int wave = t >> 6, lane = t & 63;
    if (lane == 0) { sm[wave] = m; ss[wave] = s; }
    __syncthreads();
    if (t == 0) {
        float mm = sm[0], S = ss[0];
#pragma unroll
        for (int w = 1; w < 4; ++w) {
            float mo = sm[w];
            float mn = fmaxf(mm, mo);
            S = S * __expf(mm - mn) + ss[w] * __expf(mo - mn);
            mm = mn;
        }
        vout[row] = logw - (mm + __logf(S));
    }
}

__global__ __launch_bounds__(256) void ot_value_bf16_k(const u16* __restrict__ M,
                                                       const float* __restrict__ f,
                                                       const float* __restrict__ g,
                                                       float* __restrict__ out,
                                                       float lab) {
    int row = blockIdx.x;
    const u16* Mrow = M + (size_t)row * N;
    float fi = f[row];
    int t = threadIdx.x;
    ushort8 m0 = *(const ushort8*)(Mrow + t * 8);
    ushort8 m1 = *(const ushort8*)(Mrow + 2048 + t * 8);
    fvec4 ga0 = *(const fvec4*)(g + t * 8);
    fvec4 ga1 = *(const fvec4*)(g + t * 8 + 4);
    fvec4 gb0 = *(const fvec4*)(g + 2048 + t * 8);
    fvec4 gb1 = *(const fvec4*)(g + 2048 + t * 8 + 4);
    float local = 0.f;
#pragma unroll
    for (int e = 0; e < 4; ++e) {
        float mv, lp;
        mv = bf2f(m0[e]);     lp = fi + ga0[e] - mv; local += __expf(lp) * (mv + lp - lab - 1.0f);
        mv = bf2f(m0[4 + e]); lp = fi + ga1[e] - mv; local += __expf(lp) * (mv + lp - lab - 1.0f);
        mv = bf2f(m1[e]);     lp = fi + gb0[e] - mv; local += __expf(lp) * (mv + lp - lab - 1.0f);
        mv = bf2f(m1[4 + e]); lp = fi + gb1[e] - mv; local += __expf(lp) * (mv + lp - lab - 1.0f);
    }
#pragma unroll
    for (int off = 32; off >= 1; off >>= 1) local += __shfl_down(local, off);
    __shared__ float psh[4];
    int wave = t >> 6, lane = t & 63;
    if (lane == 0) psh[wave] = local;
    __syncthreads();
    if (t == 0) {
        float sum = psh[0] + psh[1] + psh[2] + psh[3];
        if (row == 0) sum += 1.0f;
        atomicAdd(out, sum);
    }
}

extern "C" void kernel_launch(void* const* d_in, const int* in_sizes, int n_in,
                              void* d_out, int out_size, void* d_ws, size_t ws_size,
                              hipStream_t stream) {
    const float* src = (const float*)d_in[0];
    const float* tgt = (const float*)d_in[1];
    float* out = (float*)d_out;

    // workspace layout: Mb (32MB) | MTb (32MB) | Xb (4MB) | Yb (4MB) | x2 | y2 | f | g
    // barrier state + value partials alias the Xb region (dead after the GEMM).
    u16* Mb  = (u16*)d_ws;
    u16* MTb = Mb + (size_t)N * N;
    u16* Xb  = MTb + (size_t)N * N;
    u16* Yb  = Xb + (size_t)N * D;
    float* x2 = (float*)(Yb + (size_t)N * D);
    float* y2 = x2 + N;
    float* f  = y2 + N;
    float* g  = f + N;

    float* partial = (float*)Xb;                       // 1024 floats (4 KB)
    unsigned* cnt  = (unsigned*)((char*)Xb + 4096);    // 64 x 128B lines (8 KB)
    unsigned* gen  = (unsigned*)((char*)Xb + 12288);   // 64 x 128B lines (8 KB)

    const float la = -8.317766166719343f;  // -log(4096)
    const float lb = la;

    hipMemsetAsync(f, 0, 2 * N * sizeof(float), stream);  // f and g contiguous
    hipMemsetAsync(d_out, 0, sizeof(float), stream);

    f32_to_bf16_k<<<N * D / (256 * 8), 256, 0, stream>>>(src, Xb);
    f32_to_bf16_k<<<N * D / (256 * 8), 256, 0, stream>>>(tgt, Yb);
    row_norms_k<<<N / 4, 256, 0, stream>>>(src, x2);
    row_norms_k<<<N / 4, 256, 0, stream>>>(tgt, y2);
    gemm_cost_bf16_k<<<dim3(N / 128, N / 128), 256, 0, stream>>>(Xb, Yb, x2, y2, Mb);
    transpose_bf16_k<<<dim3(N / 64, N / 64), 256, 0, stream>>>(Mb, MTb);

    // zero barrier state (stream-ordered after gemm has consumed Xb)
    hipMemsetAsync(cnt, 0, 2 * 8192, stream);

    void* kargs[] = {(void*)&Mb, (void*)&MTb, (void*)&f, (void*)&g,
                     (void*)&cnt, (void*)&gen, (void*)&partial, (void*)&out};
    hipError_t cerr = hipLaunchCooperativeKernel((const void*)sinkhorn_persist_k,
                                                 dim3(NBLK), dim3(256), kargs, 0, stream);
    if (cerr != hipSuccess) {
        // fallback: previous verified 200-launch path
        for (int it = 0; it < 100; ++it) {
            sinkhorn_half_bf16_k<<<N, 256, 0, stream>>>(Mb,  g, f, la);
            sinkhorn_half_bf16_k<<<N, 256, 0, stream>>>(MTb, f, g, lb);
        }
        ot_value_bf16_k<<<N, 256, 0, stream>>>(Mb, f, g, out, la + lb);
    }
}

// Round 2
// 1644.340 us; speedup vs baseline: 7.2130x; 7.2130x over previous
//
#include <hip/hip_runtime.h>
#include <hip/hip_bf16.h>

#define N 4096
#define D 512
#define LAB1 (-16.635532333438686f - 1.0f)  // la + lb + 1

typedef unsigned short u16;
typedef __attribute__((ext_vector_type(8))) short short8;
typedef __attribute__((ext_vector_type(8))) unsigned short ushort8;
typedef __attribute__((ext_vector_type(4))) float fvec4;

static __device__ __forceinline__ unsigned short f2bf(float x) {
    __hip_bfloat16 h = __float2bfloat16(x);  // RNE
    unsigned short u;
    __builtin_memcpy(&u, &h, 2);
    return u;
}

static __device__ __forceinline__ void gld_lds16(const u16* gp, u16* lp) {
    __builtin_amdgcn_global_load_lds(
        (__attribute__((address_space(1))) void*)(u16*)gp,
        (__attribute__((address_space(3))) void*)lp, 16, 0, 0);
}

// ---------------- fp32 -> bf16 convert (8 elems/thread) ----------------
__global__ __launch_bounds__(256) void f32_to_bf16_k(const float* __restrict__ in,
                                                     u16* __restrict__ out) {
    int idx = blockIdx.x * 256 + threadIdx.x;
    fvec4 a = *((const fvec4*)in + idx * 2);
    fvec4 b = *((const fvec4*)in + idx * 2 + 1);
    ushort8 o;
#pragma unroll
    for (int e = 0; e < 4; ++e) { o[e] = f2bf(a[e]); o[4 + e] = f2bf(b[e]); }
    *((ushort8*)out + idx) = o;
}

// ---------------- row squared-norms: one wave per row ----------------
__global__ __launch_bounds__(256) void row_norms_k(const float* __restrict__ X,
                                                   float* __restrict__ out) {
    int wave = threadIdx.x >> 6;
    int lane = threadIdx.x & 63;
    int row  = blockIdx.x * 4 + wave;
    const float* xr = X + (size_t)row * D;
    float s = 0.f;
#pragma unroll
    for (int k = 0; k < D / 64; ++k) {
        float v = xr[lane + 64 * k];
        s += v * v;
    }
#pragma unroll
    for (int off = 32; off >= 1; off >>= 1) s += __shfl_down(s, off);
    if (lane == 0) out[row] = s;
}

// ---------------- cost matrix via bf16 MFMA (m97 pattern) ----------------
__global__ __launch_bounds__(256) void gemm_cost_bf16_k(const u16* __restrict__ A,
                                                        const u16* __restrict__ B,
                                                        const float* __restrict__ x2,
                                                        const float* __restrict__ y2,
                                                        u16* __restrict__ M) {
    __shared__ u16 As[128 * 32];
    __shared__ u16 Bs[128 * 32];
    int tid = threadIdx.x;
    int wave = tid >> 6, lane = tid & 63;
    int i0 = blockIdx.y * 128, j0 = blockIdx.x * 128;
    int wr = (wave >> 1) * 64, wc = (wave & 1) * 64;

    fvec4 acc[4][4] = {};

    int srow = wave * 16 + (lane >> 2);
    int skk  = (lane & 3) * 8;
    const u16* ga0 = A + (size_t)(i0 + srow) * D + skk;
    const u16* ga1 = A + (size_t)(i0 + 64 + srow) * D + skk;
    const u16* gb0 = B + (size_t)(j0 + srow) * D + skk;
    const u16* gb1 = B + (size_t)(j0 + 64 + srow) * D + skk;
    u16* la0 = &As[(wave * 16) * 32];
    u16* la1 = &As[(64 + wave * 16) * 32];
    u16* lb0 = &Bs[(wave * 16) * 32];
    u16* lb1 = &Bs[(64 + wave * 16) * 32];

    int fr = lane & 15, q = lane >> 4;

    for (int k0 = 0; k0 < D; k0 += 32) {
        __syncthreads();
        gld_lds16(ga0 + k0, la0);
        gld_lds16(ga1 + k0, la1);
        gld_lds16(gb0 + k0, lb0);
        gld_lds16(gb1 + k0, lb1);
        __syncthreads();
        short8 af[4], bf[4];
#pragma unroll
        for (int t = 0; t < 4; ++t) {
            af[t] = *(const short8*)&As[(wr + t * 16 + fr) * 32 + q * 8];
            bf[t] = *(const short8*)&Bs[(wc + t * 16 + fr) * 32 + q * 8];
        }
#pragma unroll
        for (int ri = 0; ri < 4; ++ri)
#pragma unroll
            for (int ci = 0; ci < 4; ++ci)
                acc[ri][ci] = __builtin_amdgcn_mfma_f32_16x16x32_bf16(af[ri], bf[ci],
                                                                      acc[ri][ci], 0, 0, 0);
    }

#pragma unroll
    for (int ri = 0; ri < 4; ++ri) {
#pragma unroll
        for (int ci = 0; ci < 4; ++ci) {
            int j = j0 + wc + ci * 16 + fr;
            float yj = y2[j];
#pragma unroll
            for (int r = 0; r < 4; ++r) {
                int i = i0 + wr + ri * 16 + q * 4 + r;
                float val = fmaxf(x2[i] + yj - 2.0f * acc[ri][ci][r], 0.0f);
                M[(size_t)i * N + j] = f2bf(val);
            }
        }
    }
}

// ---------------- bf16 LDS-tiled transpose ----------------
__global__ __launch_bounds__(256) void transpose_bf16_k(const u16* __restrict__ in,
                                                        u16* __restrict__ out) {
    __shared__ u16 tile[64][66];
    int bx = blockIdx.x * 64, by = blockIdx.y * 64;
    int tx = threadIdx.x & 63, ty = threadIdx.x >> 6;
#pragma unroll
    for (int r = 0; r < 64; r += 4)
        tile[r + ty][tx] = in[(size_t)(by + r + ty) * N + bx + tx];
    __syncthreads();
#pragma unroll
    for (int r = 0; r < 64; r += 4)
        out[(size_t)(bx + r + ty) * N + by + tx] = tile[tx][r + ty];
}

// ---------------- Sinkhorn half-step: one row per WAVE ----------------
// vout[row] = logw - LSE_j( vin[j] - R[row][j] )
// Grid 1024 x 256: 4 waves/block, 4 blocks/CU co-resident, no __syncthreads,
// no LDS, no cross-wave merge. Online (m,s) merge over 8 chunks of 8 elems.
__global__ __launch_bounds__(256, 4) void sinkhorn_half_w_k(const u16* __restrict__ Mr,
                                                            const float* __restrict__ vin,
                                                            float* __restrict__ vout,
                                                            float logw) {
    int wid  = (blockIdx.x << 2) | (threadIdx.x >> 6);  // row 0..4095
    int lane = threadIdx.x & 63;
    const u16* row = Mr + ((size_t)wid << 12);
    float m = -1e30f, s = 0.f;
#pragma unroll
    for (int c = 0; c < 8; ++c) {
        int j = c * 512 + lane * 8;
        ushort8 m8 = *(const ushort8*)(row + j);
        fvec4 g0 = *(const fvec4*)(vin + j);
        fvec4 g1 = *(const fvec4*)(vin + j + 4);
        const unsigned* mu = (const unsigned*)&m8;
        float tv[8];
#pragma unroll
        for (int k = 0; k < 4; ++k) {
            unsigned u = mu[k];
            float flo = __uint_as_float(u << 16);          // elem 2k
            float fhi = __uint_as_float(u & 0xffff0000u);  // elem 2k+1
            float ga = (k < 2) ? g0[2 * k] : g1[2 * k - 4];
            float gb = (k < 2) ? g0[2 * k + 1] : g1[2 * k - 3];
            tv[2 * k]     = ga - flo;
            tv[2 * k + 1] = gb - fhi;
        }
        float mh = tv[0];
#pragma unroll
        for (int e = 1; e < 8; ++e) mh = fmaxf(mh, tv[e]);
        float sh = 0.f;
#pragma unroll
        for (int e = 0; e < 8; ++e) sh += __expf(tv[e] - mh);
        float mn = fmaxf(m, mh);
        s = s * __expf(m - mn) + sh * __expf(mh - mn);
        m = mn;
    }
#pragma unroll
    for (int off = 32; off >= 1; off >>= 1) {
        float mo = __shfl_xor(m, off);
        float so = __shfl_xor(s, off);
        float mn = fmaxf(m, mo);
        s = s * __expf(m - mn) + so * __expf(mo - mn);
        m = mn;
    }
    if (lane == 0) vout[wid] = logw - (m + __logf(s));
}

// ---------------- objective partials: one row per wave, no atomics ----------
__global__ __launch_bounds__(256, 4) void ot_value_w_k(const u16* __restrict__ M,
                                                       const float* __restrict__ f,
                                                       const float* __restrict__ g,
                                                       float* __restrict__ partial) {
    int wid  = (blockIdx.x << 2) | (threadIdx.x >> 6);
    int lane = threadIdx.x & 63;
    const u16* row = M + ((size_t)wid << 12);
    float fi = f[wid];
    float local = 0.f;
#pragma unroll
    for (int c = 0; c < 8; ++c) {
        int j = c * 512 + lane * 8;
        ushort8 m8 = *(const ushort8*)(row + j);
        fvec4 g0 = *(const fvec4*)(g + j);
        fvec4 g1 = *(const fvec4*)(g + j + 4);
        const unsigned* mu = (const unsigned*)&m8;
#pragma unroll
        for (int k = 0; k < 4; ++k) {
            unsigned u = mu[k];
            float mv0 = __uint_as_float(u << 16);
            float mv1 = __uint_as_float(u & 0xffff0000u);
            float ga = (k < 2) ? g0[2 * k] : g1[2 * k - 4];
            float gb = (k < 2) ? g0[2 * k + 1] : g1[2 * k - 3];
            float a0 = fi + ga, a1 = fi + gb;
            local += __expf(a0 - mv0) * (a0 - LAB1);
            local += __expf(a1 - mv1) * (a1 - LAB1);
        }
    }
#pragma unroll
    for (int off = 32; off >= 1; off >>= 1) local += __shfl_xor(local, off);
    __shared__ float ps[4];
    if (lane == 0) ps[threadIdx.x >> 6] = local;
    __syncthreads();
    if (threadIdx.x == 0) partial[blockIdx.x] = ps[0] + ps[1] + ps[2] + ps[3];
}

__global__ __launch_bounds__(256) void value_reduce_k(const float* __restrict__ partial,
                                                      float* __restrict__ out) {
    int t = threadIdx.x;
    float s = partial[t] + partial[t + 256] + partial[t + 512] + partial[t + 768];
#pragma unroll
    for (int off = 32; off >= 1; off >>= 1) s += __shfl_xor(s, off);
    __shared__ float fs[4];
    if ((t & 63) == 0) fs[t >> 6] = s;
    __syncthreads();
    if (t == 0) out[0] = fs[0] + fs[1] + fs[2] + fs[3] + 1.0f;
}

extern "C" void kernel_launch(void* const* d_in, const int* in_sizes, int n_in,
                              void* d_out, int out_size, void* d_ws, size_t ws_size,
                              hipStream_t stream) {
    const float* src = (const float*)d_in[0];
    const float* tgt = (const float*)d_in[1];
    float* out = (float*)d_out;

    // workspace layout: Mb (32MB) | MTb (32MB) | Xb (4MB) | Yb (4MB) | x2 | y2 | f | g
    // value partials alias the Xb region (dead after the GEMM).
    u16* Mb  = (u16*)d_ws;
    u16* MTb = Mb + (size_t)N * N;
    u16* Xb  = MTb + (size_t)N * N;
    u16* Yb  = Xb + (size_t)N * D;
    float* x2 = (float*)(Yb + (size_t)N * D);
    float* y2 = x2 + N;
    float* f  = y2 + N;
    float* g  = f + N;

    float* partial = (float*)Xb;  // 1024 floats (4 KB)

    const float la = -8.317766166719343f;  // -log(4096)
    const float lb = la;

    hipMemsetAsync(f, 0, 2 * N * sizeof(float), stream);  // f and g contiguous

    f32_to_bf16_k<<<N * D / (256 * 8), 256, 0, stream>>>(src, Xb);
    f32_to_bf16_k<<<N * D / (256 * 8), 256, 0, stream>>>(tgt, Yb);
    row_norms_k<<<N / 4, 256, 0, stream>>>(src, x2);
    row_norms_k<<<N / 4, 256, 0, stream>>>(tgt, y2);
    gemm_cost_bf16_k<<<dim3(N / 128, N / 128), 256, 0, stream>>>(Xb, Yb, x2, y2, Mb);
    transpose_bf16_k<<<dim3(N / 64, N / 64), 256, 0, stream>>>(Mb, MTb);

    for (int it = 0; it < 100; ++it) {
        sinkhorn_half_w_k<<<N / 4, 256, 0, stream>>>(Mb,  g, f, la);
        sinkhorn_half_w_k<<<N / 4, 256, 0, stream>>>(MTb, f, g, lb);
    }

    ot_value_w_k<<<N / 4, 256, 0, stream>>>(Mb, f, g, partial);
    value_reduce_k<<<1, 256, 0, stream>>>(partial, out);
}